// Round 9
// baseline (161.425 us; speedup 1.0000x reference)
//
#include <hip/hip_runtime.h>

// out[b,g] = sum_f x[b,3g+f]*w[3g+f] + bias[g];  B=4096, G=9229, F=3, fp32.
//
// Flat decomposition (R7): output i = b*G+g <-> x floats 3i..3i+2, seamless
// across rows. Unit = 256 outputs = 192 aligned x-f4s read + 64 aligned
// out-f4s written. NT on both streams; w/bias cached.
// R8 changes vs R7:
//  - no setup kernel / no wext: w,bias read directly; the 2.8% of units
//    whose gene window wraps (g0 > 8973, wave-uniform test) take a scalar
//    wrapped-index path.
//  - unroll-2: each wave processes units u and u+8192 per iteration, all
//    6 NT loads issued before either compute (2x memory-level parallelism).
//  - no forced (256,8) occupancy bound (R7's 64-VGPR cap was starving the
//    body); 16 waves/CU is ample for a streaming kernel.
// In-register shuffle reassembly identical to R5-R7 (verified):
//   f4 j (slot s=j/64, lane t=j%64), m=(s+t)%3:
//   m=0: gene4k=p0+p1+p2; gene4k+1=p3+next(p0+p1)
//   m=1: gene4k+2=p2+p3+next(p0); m=2: gene4k+3=p1+p2+p3
//   ring shfl(t+1), lane63 slot-wrap; output transpose via 4 pull-shfls.

#define G      9229u
#define GFW    27687u            // 3*G
#define NUNIT  147664u           // 37,801,984 / 256
#define NWAVES 8192u             // grid 2048 x 4 waves (exact, no idle waves)

typedef float f32x4 __attribute__((ext_vector_type(4)));

__device__ __forceinline__ void load_wb(
    const float* __restrict__ w, const float* __restrict__ bias,
    unsigned g0, int t,
    float4& w0, float4& w1, float4& w2, float4& bv) {
    const unsigned wf0 = 3u * g0;
    if (g0 <= 8973u) {   // window genes g0..g0+255 all < G: no wrap
        w0 = *reinterpret_cast<const float4*>(w + wf0 + 4 * t);
        w1 = *reinterpret_cast<const float4*>(w + wf0 + 256 + 4 * t);
        w2 = *reinterpret_cast<const float4*>(w + wf0 + 512 + 4 * t);
        bv = *reinterpret_cast<const float4*>(bias + g0 + 4 * t);
    } else {             // wrap path (wave-uniform; 255/9229 of units)
        float wt[12], bt[4];
#pragma unroll
        for (int c = 0; c < 4; ++c) {
            unsigned i0 = wf0 + 4u * t + c;        if (i0 >= GFW) i0 -= GFW;
            unsigned i1 = wf0 + 256u + 4u * t + c; if (i1 >= GFW) i1 -= GFW;
            unsigned i2 = wf0 + 512u + 4u * t + c; if (i2 >= GFW) i2 -= GFW;
            wt[c] = w[i0]; wt[4 + c] = w[i1]; wt[8 + c] = w[i2];
            unsigned ib = g0 + 4u * t + c;         if (ib >= G) ib -= G;
            bt[c] = bias[ib];
        }
        w0 = make_float4(wt[0], wt[1], wt[2], wt[3]);
        w1 = make_float4(wt[4], wt[5], wt[6], wt[7]);
        w2 = make_float4(wt[8], wt[9], wt[10], wt[11]);
        bv = make_float4(bt[0], bt[1], bt[2], bt[3]);
    }
}

__device__ __forceinline__ void compute_store(
    f32x4 v0, f32x4 v1, f32x4 v2,
    float4 w0, float4 w1, float4 w2, float4 bv,
    int t, int tm, bool last, int srcA, int srcC, int srcD,
    float* __restrict__ dst) {
    const float a0 = v0.x * w0.x, a1 = v0.y * w0.y, a2 = v0.z * w0.z, a3 = v0.w * w0.w;
    const float q01_0 = a0 + a1, q23_0 = a2 + a3;
    const float q012_0 = q01_0 + a2, q123_0 = q23_0 + a1;
    const float b0 = v1.x * w1.x, b1 = v1.y * w1.y, b2 = v1.z * w1.z, b3 = v1.w * w1.w;
    const float q01_1 = b0 + b1, q23_1 = b2 + b3;
    const float q012_1 = q01_1 + b2, q123_1 = q23_1 + b1;
    const float c0 = v2.x * w2.x, c1 = v2.y * w2.y, c2 = v2.z * w2.z, c3 = v2.w * w2.w;
    const float q01_2 = c0 + c1, q23_2 = c2 + c3;
    const float q012_2 = q01_2 + c2, q123_2 = q23_2 + c1;

    // ring exchange: pred (f4 j-1) needs: m==1 -> p0+p1 ; m==2 -> p0
    const float s0 = (tm == 1) ? q01_0 : a0;
    const float s1 = (tm == 0) ? q01_1 : b0;
    const float s2 = (tm == 2) ? q01_2 : c0;
    const float r0 = __shfl(s0, (t + 1) & 63);
    const float r1 = __shfl(s1, (t + 1) & 63);
    const float r2 = __shfl(s2, (t + 1) & 63);
    const float E0 = last ? r1 : r0;
    const float E1 = last ? r2 : r1;
    const float E2 = r2;

    const float bb0 = a3 + E0, bb1 = b3 + E1, bb2 = c3 + E2;
    const float cc0 = q23_0 + E0, cc1 = q23_1 + E1, cc2 = q23_2 + E2;

    const float A  = (tm == 0) ? q012_0 : (tm == 2) ? q012_1 : q012_2;
    const float Bv = (tm == 0) ? bb0   : (tm == 2) ? bb1   : bb2;
    const float C  = (tm == 1) ? cc0   : (tm == 0) ? cc1   : cc2;
    const float D  = (tm == 2) ? q123_0 : (tm == 1) ? q123_1 : q123_2;

    f32x4 o;
    o.x = __shfl(A,  srcA) + bv.x;
    o.y = __shfl(Bv, srcA) + bv.y;
    o.z = __shfl(C,  srcC) + bv.z;
    o.w = __shfl(D,  srcD) + bv.w;
    __builtin_nontemporal_store(o, reinterpret_cast<f32x4*>(dst));
}

__global__ __launch_bounds__(256) void diag_flat2_kernel(
    const float* __restrict__ x,
    const float* __restrict__ w,
    const float* __restrict__ bias,
    float* __restrict__ out) {

    const int t  = (int)(threadIdx.x & 63);
    const int wv = (int)blockIdx.x * 4 + (int)(threadIdx.x >> 6);

    const int tm    = t % 3;
    const bool last = (t == 63);
    const int srcA = (3 * t) & 63;
    const int srcC = (3 * t + 1) & 63;
    const int srcD = (3 * t + 2) & 63;

    // 18 full strided units per wave (9 unroll-2 pairs) + 208-wave tail.
    for (unsigned k = 0; k < 18; k += 2) {
        const unsigned uA = (unsigned)wv + k * NWAVES;
        const unsigned uB = uA + NWAVES;
        const float* xrA = x + 768u * uA;
        const float* xrB = x + 768u * uB;

        // Issue all 6 NT loads before any compute (2x MLP vs R7).
        const f32x4 a0 = __builtin_nontemporal_load(reinterpret_cast<const f32x4*>(xrA + 4 * t));
        const f32x4 a1 = __builtin_nontemporal_load(reinterpret_cast<const f32x4*>(xrA + 256 + 4 * t));
        const f32x4 a2 = __builtin_nontemporal_load(reinterpret_cast<const f32x4*>(xrA + 512 + 4 * t));
        const f32x4 b0 = __builtin_nontemporal_load(reinterpret_cast<const f32x4*>(xrB + 4 * t));
        const f32x4 b1 = __builtin_nontemporal_load(reinterpret_cast<const f32x4*>(xrB + 256 + 4 * t));
        const f32x4 b2 = __builtin_nontemporal_load(reinterpret_cast<const f32x4*>(xrB + 512 + 4 * t));

        float4 wA0, wA1, wA2, bvA, wB0, wB1, wB2, bvB;
        load_wb(w, bias, (256u * uA) % G, t, wA0, wA1, wA2, bvA);
        load_wb(w, bias, (256u * uB) % G, t, wB0, wB1, wB2, bvB);

        compute_store(a0, a1, a2, wA0, wA1, wA2, bvA, t, tm, last, srcA, srcC, srcD,
                      out + 256u * uA + 4 * t);
        compute_store(b0, b1, b2, wB0, wB1, wB2, bvB, t, tm, last, srcA, srcC, srcD,
                      out + 256u * uB + 4 * t);
    }

    // Tail: NUNIT = 18*8192 + 208 -> waves 0..207 process one more unit.
    if (wv < (int)(NUNIT - 18u * NWAVES)) {
        const unsigned u = 18u * NWAVES + (unsigned)wv;
        const float* xr = x + 768u * u;
        const f32x4 v0 = __builtin_nontemporal_load(reinterpret_cast<const f32x4*>(xr + 4 * t));
        const f32x4 v1 = __builtin_nontemporal_load(reinterpret_cast<const f32x4*>(xr + 256 + 4 * t));
        const f32x4 v2 = __builtin_nontemporal_load(reinterpret_cast<const f32x4*>(xr + 512 + 4 * t));
        float4 w0, w1, w2, bv;
        load_wb(w, bias, (256u * u) % G, t, w0, w1, w2, bv);
        compute_store(v0, v1, v2, w0, w1, w2, bv, t, tm, last, srcA, srcC, srcD,
                      out + 256u * u + 4 * t);
    }
}

extern "C" void kernel_launch(void* const* d_in, const int* in_sizes, int n_in,
                              void* d_out, int out_size, void* d_ws, size_t ws_size,
                              hipStream_t stream) {
    const float* x    = (const float*)d_in[0];
    const float* w    = (const float*)d_in[1];
    const float* bias = (const float*)d_in[2];
    float* out        = (float*)d_out;

    diag_flat2_kernel<<<2048, 256, 0, stream>>>(x, w, bias, out);
}

// Round 10
// 122.033 us; speedup vs baseline: 1.3228x; 1.3228x over previous
//
#include <hip/hip_runtime.h>

// out[b,g] = sum_f x[b,3g+f]*w[3g+f] + bias[g];  B=4096, G=9229, F=3, fp32.
//
// Flat decomposition (R7, verified): output i = b*G+g <-> x floats 3i..3i+2.
// Unit = 256 outputs = 192 aligned x-f4s + 64 aligned out-f4s, NT both ways.
// Weight wrap handled by wrap-extended copies wext/bext in d_ws (setup
// kernel, as in R7).
//
// R9 single change vs R7: CLASS-MAJOR unit ordering. NUNIT = 16*G exactly,
// and units u = c (mod G) share the same gene window g0 = 256c mod G.
// idx = c*16 + k  ->  u = c + G*k. Each wave takes 18-19 consecutive idx
// -> w/bias loaded once per class-chunk (every 8-16 units) instead of per
// unit (R7: 4 cached L1-missing loads per unit = 36% of load instrs).
// Inner loop: 3 NT loads + compute + 1 NT store, nothing else.
// Balance: waves 0..207 take 19 units, rest 18 -> <1% stretch.
//
// Shuffle reassembly (verified R5-R8):
//   f4 j (slot s=j/64, lane t=j%64), m=(s+t)%3:
//   m=0: gene4k=p0+p1+p2; gene4k+1=p3+next(p0+p1)
//   m=1: gene4k+2=p2+p3+next(p0); m=2: gene4k+3=p1+p2+p3
//   ring shfl(t+1), lane63 slot-wrap; output transpose via 4 pull-shfls.

#define G        9229u
#define GFW      27687u           // 3*G
#define NUNIT    147664u          // 16 * G exactly
#define NWAVES   8192u            // grid 2048 x 4 waves
#define WEXT_N   (27687 + 768)    // 28455
#define BEXT_OFF 28456            // 16B-aligned float offset of bext
#define BEXT_N   (9229 + 256)     // 9485
#define WS_FLOATS (BEXT_OFF + BEXT_N)

typedef float f32x4 __attribute__((ext_vector_type(4)));

__global__ __launch_bounds__(256) void build_ext_kernel(
    const float* __restrict__ w, const float* __restrict__ bias,
    float* __restrict__ ws) {
    const int i = (int)blockIdx.x * 256 + (int)threadIdx.x;
    if (i < WEXT_N) {
        ws[i] = w[i >= (int)GFW ? i - (int)GFW : i];
    } else {
        const int k = i - WEXT_N;
        if (k < BEXT_N) ws[BEXT_OFF + k] = bias[k >= (int)G ? k - (int)G : k];
    }
}

__global__ __launch_bounds__(256, 8) void diag_class_kernel(
    const float* __restrict__ x,
    const float* __restrict__ ws,
    float* __restrict__ out) {

    const float* wext = ws;
    const float* bext = ws + BEXT_OFF;

    const int t  = (int)(threadIdx.x & 63);
    const int wv = (int)blockIdx.x * 4 + (int)(threadIdx.x >> 6);

    const int tm    = t % 3;
    const bool last = (t == 63);
    const int srcA = (3 * t) & 63;
    const int srcC = (3 * t + 1) & 63;
    const int srcD = (3 * t + 2) & 63;

    const unsigned cnt  = 18u + ((unsigned)wv < 208u ? 1u : 0u);
    unsigned idx        = 18u * (unsigned)wv + ((unsigned)wv < 208u ? (unsigned)wv : 208u);
    const unsigned end  = idx + cnt;

    while (idx < end) {
        const unsigned c    = idx >> 4;
        const unsigned k0   = idx & 15u;
        const unsigned rem  = end - (c << 4);          // idx-room within this class
        const unsigned kend = rem < 16u ? rem : 16u;
        const unsigned g0   = (256u * c) % G;          // magic-multiply
        const unsigned wf0  = 3u * g0;

        // class weights/bias: loaded once per class-chunk (cached path)
        const float4 w0 = *reinterpret_cast<const float4*>(wext + wf0 + 4 * t);
        const float4 w1 = *reinterpret_cast<const float4*>(wext + wf0 + 256 + 4 * t);
        const float4 w2 = *reinterpret_cast<const float4*>(wext + wf0 + 512 + 4 * t);
        const float4 bv = *reinterpret_cast<const float4*>(bext + g0 + 4 * t);

        for (unsigned k = k0; k < kend; ++k) {
            const unsigned u  = c + G * k;
            const float* xr   = x + 768u * u;          // 16B-aligned

            const f32x4 v0 = __builtin_nontemporal_load(
                reinterpret_cast<const f32x4*>(xr + 4 * t));
            const f32x4 v1 = __builtin_nontemporal_load(
                reinterpret_cast<const f32x4*>(xr + 256 + 4 * t));
            const f32x4 v2 = __builtin_nontemporal_load(
                reinterpret_cast<const f32x4*>(xr + 512 + 4 * t));

            const float a0 = v0.x * w0.x, a1 = v0.y * w0.y, a2 = v0.z * w0.z, a3 = v0.w * w0.w;
            const float q01_0 = a0 + a1, q23_0 = a2 + a3;
            const float q012_0 = q01_0 + a2, q123_0 = q23_0 + a1;
            const float b0 = v1.x * w1.x, b1 = v1.y * w1.y, b2 = v1.z * w1.z, b3 = v1.w * w1.w;
            const float q01_1 = b0 + b1, q23_1 = b2 + b3;
            const float q012_1 = q01_1 + b2, q123_1 = q23_1 + b1;
            const float c0 = v2.x * w2.x, c1 = v2.y * w2.y, c2 = v2.z * w2.z, c3 = v2.w * w2.w;
            const float q01_2 = c0 + c1, q23_2 = c2 + c3;
            const float q012_2 = q01_2 + c2, q123_2 = q23_2 + c1;

            // ring exchange: pred (f4 j-1) needs: m==1 -> p0+p1 ; m==2 -> p0
            const float s0 = (tm == 1) ? q01_0 : a0;
            const float s1 = (tm == 0) ? q01_1 : b0;
            const float s2 = (tm == 2) ? q01_2 : c0;
            const float r0 = __shfl(s0, (t + 1) & 63);
            const float r1 = __shfl(s1, (t + 1) & 63);
            const float r2 = __shfl(s2, (t + 1) & 63);
            const float E0 = last ? r1 : r0;
            const float E1 = last ? r2 : r1;
            const float E2 = r2;

            const float bb0 = a3 + E0, bb1 = b3 + E1, bb2 = c3 + E2;
            const float cc0 = q23_0 + E0, cc1 = q23_1 + E1, cc2 = q23_2 + E2;

            const float A  = (tm == 0) ? q012_0 : (tm == 2) ? q012_1 : q012_2;
            const float Bv = (tm == 0) ? bb0   : (tm == 2) ? bb1   : bb2;
            const float C  = (tm == 1) ? cc0   : (tm == 0) ? cc1   : cc2;
            const float D  = (tm == 2) ? q123_0 : (tm == 1) ? q123_1 : q123_2;

            f32x4 o;
            o.x = __shfl(A,  srcA) + bv.x;
            o.y = __shfl(Bv, srcA) + bv.y;
            o.z = __shfl(C,  srcC) + bv.z;
            o.w = __shfl(D,  srcD) + bv.w;

            __builtin_nontemporal_store(
                o, reinterpret_cast<f32x4*>(out + 256u * u + 4 * t));
        }
        idx = (c << 4) + kend;
    }
}

extern "C" void kernel_launch(void* const* d_in, const int* in_sizes, int n_in,
                              void* d_out, int out_size, void* d_ws, size_t ws_size,
                              hipStream_t stream) {
    const float* x    = (const float*)d_in[0];
    const float* w    = (const float*)d_in[1];
    const float* bias = (const float*)d_in[2];
    float* out        = (float*)d_out;
    float* ws         = (float*)d_ws;

    build_ext_kernel<<<(WEXT_N + BEXT_N + 255) / 256, 256, 0, stream>>>(w, bias, ws);
    diag_class_kernel<<<2048, 256, 0, stream>>>(x, ws, out);
}

// Round 11
// 121.986 us; speedup vs baseline: 1.3233x; 1.0004x over previous
//
#include <hip/hip_runtime.h>

// out[b,g] = sum_f x[b,3g+f]*w[3g+f] + bias[g];  B=4096, G=9229, F=3, fp32.
//
// EXACT R7 structure (best: 119.0 us), ONE change: out stores are normal
// cached float4 (NT removed from stores only; NT loads kept). Theory: the
// 151 MB write stream drains better through L2 write-combining than via
// NT direct-to-HBM (harness fill kernels sustain ~7 TB/s with cached
// writes); A/B vs R7's NT-store.
//
// Flat decomposition: output i = b*G+g <-> x floats 3i..3i+2 (seamless
// across rows). Unit = 256 outputs = 192 aligned x-f4s + 64 aligned
// out-f4s. Weight wrap via wrap-extended wext/bext in d_ws (setup kernel).
// Shuffle reassembly (verified R5-R9):
//   f4 j (slot s=j/64, lane t=j%64), m=(s+t)%3:
//   m=0: gene4k=p0+p1+p2; gene4k+1=p3+next(p0+p1)
//   m=1: gene4k+2=p2+p3+next(p0); m=2: gene4k+3=p1+p2+p3
//   ring shfl(t+1), lane63 slot-wrap; output transpose via 4 pull-shfls.

#define G       9229
#define GFW     27687            // 3*G
#define NUNIT   147664           // 37,801,984 / 256
#define NWAVES  8192             // grid 2048 x 4 waves
#define WEXT_N  (GFW + 768)      // 28455
#define BEXT_OFF 28456           // float offset of bext in ws (16B aligned)
#define BEXT_N  (G + 256)        // 9485
#define WS_FLOATS (BEXT_OFF + BEXT_N)   // 37941 -> 151764 bytes

typedef float f32x4 __attribute__((ext_vector_type(4)));

__global__ __launch_bounds__(256) void build_ext_kernel(
    const float* __restrict__ w, const float* __restrict__ bias,
    float* __restrict__ ws) {
    const int i = (int)blockIdx.x * 256 + (int)threadIdx.x;
    if (i < WEXT_N) {
        ws[i] = w[i >= GFW ? i - GFW : i];
    } else {
        const int k = i - WEXT_N;
        if (k < BEXT_N) ws[BEXT_OFF + k] = bias[k >= G ? k - G : k];
    }
}

__global__ __launch_bounds__(256, 8) void diag_flat_kernel(
    const float* __restrict__ x,
    const float* __restrict__ ws,
    float* __restrict__ out) {

    const float* wext = ws;
    const float* bext = ws + BEXT_OFF;

    const int t  = (int)(threadIdx.x & 63);
    const int wv = (int)blockIdx.x * 4 + (int)(threadIdx.x >> 6);

    const int tm    = t % 3;
    const bool last = (t == 63);
    const int srcA = (3 * t) & 63;
    const int srcC = (3 * t + 1) & 63;
    const int srcD = (3 * t + 2) & 63;

    for (unsigned u = (unsigned)wv; u < NUNIT; u += NWAVES) {
        const unsigned O0  = 256u * u;          // first output of unit
        const unsigned g0  = O0 % (unsigned)G;  // gene of first output
        const unsigned wf0 = 3u * g0;           // weight float base (wrap-free in wext)
        const float* xr = x + 768u * u;         // 16B-aligned

        const f32x4 v0 = __builtin_nontemporal_load(
            reinterpret_cast<const f32x4*>(xr + 4 * t));
        const f32x4 v1 = __builtin_nontemporal_load(
            reinterpret_cast<const f32x4*>(xr + 256 + 4 * t));
        const f32x4 v2 = __builtin_nontemporal_load(
            reinterpret_cast<const f32x4*>(xr + 512 + 4 * t));

        // cached, dword-aligned (16B-misaligned ok), L1/L2-resident
        const float4 w0 = *reinterpret_cast<const float4*>(wext + wf0 + 4 * t);
        const float4 w1 = *reinterpret_cast<const float4*>(wext + wf0 + 256 + 4 * t);
        const float4 w2 = *reinterpret_cast<const float4*>(wext + wf0 + 512 + 4 * t);
        const float4 bv = *reinterpret_cast<const float4*>(bext + g0 + 4 * t);

        // slot products / partials
        const float a0 = v0.x * w0.x, a1 = v0.y * w0.y, a2 = v0.z * w0.z, a3 = v0.w * w0.w;
        const float q01_0 = a0 + a1, q23_0 = a2 + a3;
        const float q012_0 = q01_0 + a2, q123_0 = q23_0 + a1;
        const float b0 = v1.x * w1.x, b1 = v1.y * w1.y, b2 = v1.z * w1.z, b3 = v1.w * w1.w;
        const float q01_1 = b0 + b1, q23_1 = b2 + b3;
        const float q012_1 = q01_1 + b2, q123_1 = q23_1 + b1;
        const float c0 = v2.x * w2.x, c1 = v2.y * w2.y, c2 = v2.z * w2.z, c3 = v2.w * w2.w;
        const float q01_2 = c0 + c1, q23_2 = c2 + c3;
        const float q012_2 = q01_2 + c2, q123_2 = q23_2 + c1;

        // ring exchange: pred (f4 j-1) needs: m==1 -> p0+p1 ; m==2 -> p0
        const float s0 = (tm == 1) ? q01_0 : a0;
        const float s1 = (tm == 0) ? q01_1 : b0;
        const float s2 = (tm == 2) ? q01_2 : c0;
        const float r0 = __shfl(s0, (t + 1) & 63);
        const float r1 = __shfl(s1, (t + 1) & 63);
        const float r2 = __shfl(s2, (t + 1) & 63);
        const float E0 = last ? r1 : r0;
        const float E1 = last ? r2 : r1;
        const float E2 = r2;

        const float bb0 = a3 + E0, bb1 = b3 + E1, bb2 = c3 + E2;
        const float cc0 = q23_0 + E0, cc1 = q23_1 + E1, cc2 = q23_2 + E2;

        const float A  = (tm == 0) ? q012_0 : (tm == 2) ? q012_1 : q012_2;
        const float Bv = (tm == 0) ? bb0   : (tm == 2) ? bb1   : bb2;
        const float C  = (tm == 1) ? cc0   : (tm == 0) ? cc1   : cc2;
        const float D  = (tm == 2) ? q123_0 : (tm == 1) ? q123_1 : q123_2;

        f32x4 o;
        o.x = __shfl(A,  srcA) + bv.x;
        o.y = __shfl(Bv, srcA) + bv.y;
        o.z = __shfl(C,  srcC) + bv.z;
        o.w = __shfl(D,  srcD) + bv.w;

        // ONE CHANGE vs R7: normal cached store (was nontemporal).
        *reinterpret_cast<f32x4*>(out + O0 + 4 * t) = o;   // 16B-aligned
    }
}

extern "C" void kernel_launch(void* const* d_in, const int* in_sizes, int n_in,
                              void* d_out, int out_size, void* d_ws, size_t ws_size,
                              hipStream_t stream) {
    const float* x    = (const float*)d_in[0];
    const float* w    = (const float*)d_in[1];
    const float* bias = (const float*)d_in[2];
    float* out        = (float*)d_out;
    float* ws         = (float*)d_ws;

    build_ext_kernel<<<(WEXT_N + BEXT_N + 255) / 256, 256, 0, stream>>>(w, bias, ws);
    diag_flat_kernel<<<2048, 256, 0, stream>>>(x, ws, out);
}

// Round 12
// 120.555 us; speedup vs baseline: 1.3390x; 1.0119x over previous
//
#include <hip/hip_runtime.h>

// out[b,g] = sum_f x[b,3g+f]*w[3g+f] + bias[g];  B=4096, G=9229, F=3, fp32.
//
// EXACT R7 structure (best: 119.0 us, NT loads + NT stores), ONE change:
// grid 2048 -> 1024 (16 waves/CU instead of 32). Theory: 32 waves/CU x 4
// address streams = 32K concurrent 1KB streams device-wide thrashes DRAM
// row buffers; fills hit 7 TB/s at ~3.5 waves/CU. 16 waves/CU still has
// 5x the in-flight bytes needed for latency hiding (48KB vs 9.2KB/CU).
//
// Flat decomposition: output i = b*G+g <-> x floats 3i..3i+2 (seamless
// across rows). Unit = 256 outputs = 192 aligned x-f4s + 64 aligned
// out-f4s. Weight wrap via wrap-extended wext/bext in d_ws (setup kernel).
// Shuffle reassembly (verified R5-R10):
//   f4 j (slot s=j/64, lane t=j%64), m=(s+t)%3:
//   m=0: gene4k=p0+p1+p2; gene4k+1=p3+next(p0+p1)
//   m=1: gene4k+2=p2+p3+next(p0); m=2: gene4k+3=p1+p2+p3
//   ring shfl(t+1), lane63 slot-wrap; output transpose via 4 pull-shfls.

#define G       9229
#define GFW     27687            // 3*G
#define NUNIT   147664           // 37,801,984 / 256
#define NWAVES  4096             // grid 1024 x 4 waves  (ONE CHANGE vs R7)
#define WEXT_N  (GFW + 768)      // 28455
#define BEXT_OFF 28456           // float offset of bext in ws (16B aligned)
#define BEXT_N  (G + 256)        // 9485
#define WS_FLOATS (BEXT_OFF + BEXT_N)   // 37941 -> 151764 bytes

typedef float f32x4 __attribute__((ext_vector_type(4)));

__global__ __launch_bounds__(256) void build_ext_kernel(
    const float* __restrict__ w, const float* __restrict__ bias,
    float* __restrict__ ws) {
    const int i = (int)blockIdx.x * 256 + (int)threadIdx.x;
    if (i < WEXT_N) {
        ws[i] = w[i >= GFW ? i - GFW : i];
    } else {
        const int k = i - WEXT_N;
        if (k < BEXT_N) ws[BEXT_OFF + k] = bias[k >= G ? k - G : k];
    }
}

__global__ __launch_bounds__(256, 8) void diag_flat_kernel(
    const float* __restrict__ x,
    const float* __restrict__ ws,
    float* __restrict__ out) {

    const float* wext = ws;
    const float* bext = ws + BEXT_OFF;

    const int t  = (int)(threadIdx.x & 63);
    const int wv = (int)blockIdx.x * 4 + (int)(threadIdx.x >> 6);

    const int tm    = t % 3;
    const bool last = (t == 63);
    const int srcA = (3 * t) & 63;
    const int srcC = (3 * t + 1) & 63;
    const int srcD = (3 * t + 2) & 63;

    for (unsigned u = (unsigned)wv; u < NUNIT; u += NWAVES) {
        const unsigned O0  = 256u * u;          // first output of unit
        const unsigned g0  = O0 % (unsigned)G;  // gene of first output
        const unsigned wf0 = 3u * g0;           // weight float base (wrap-free in wext)
        const float* xr = x + 768u * u;         // 16B-aligned

        const f32x4 v0 = __builtin_nontemporal_load(
            reinterpret_cast<const f32x4*>(xr + 4 * t));
        const f32x4 v1 = __builtin_nontemporal_load(
            reinterpret_cast<const f32x4*>(xr + 256 + 4 * t));
        const f32x4 v2 = __builtin_nontemporal_load(
            reinterpret_cast<const f32x4*>(xr + 512 + 4 * t));

        // cached, dword-aligned (16B-misaligned ok), L1/L2-resident
        const float4 w0 = *reinterpret_cast<const float4*>(wext + wf0 + 4 * t);
        const float4 w1 = *reinterpret_cast<const float4*>(wext + wf0 + 256 + 4 * t);
        const float4 w2 = *reinterpret_cast<const float4*>(wext + wf0 + 512 + 4 * t);
        const float4 bv = *reinterpret_cast<const float4*>(bext + g0 + 4 * t);

        // slot products / partials
        const float a0 = v0.x * w0.x, a1 = v0.y * w0.y, a2 = v0.z * w0.z, a3 = v0.w * w0.w;
        const float q01_0 = a0 + a1, q23_0 = a2 + a3;
        const float q012_0 = q01_0 + a2, q123_0 = q23_0 + a1;
        const float b0 = v1.x * w1.x, b1 = v1.y * w1.y, b2 = v1.z * w1.z, b3 = v1.w * w1.w;
        const float q01_1 = b0 + b1, q23_1 = b2 + b3;
        const float q012_1 = q01_1 + b2, q123_1 = q23_1 + b1;
        const float c0 = v2.x * w2.x, c1 = v2.y * w2.y, c2 = v2.z * w2.z, c3 = v2.w * w2.w;
        const float q01_2 = c0 + c1, q23_2 = c2 + c3;
        const float q012_2 = q01_2 + c2, q123_2 = q23_2 + c1;

        // ring exchange: pred (f4 j-1) needs: m==1 -> p0+p1 ; m==2 -> p0
        const float s0 = (tm == 1) ? q01_0 : a0;
        const float s1 = (tm == 0) ? q01_1 : b0;
        const float s2 = (tm == 2) ? q01_2 : c0;
        const float r0 = __shfl(s0, (t + 1) & 63);
        const float r1 = __shfl(s1, (t + 1) & 63);
        const float r2 = __shfl(s2, (t + 1) & 63);
        const float E0 = last ? r1 : r0;
        const float E1 = last ? r2 : r1;
        const float E2 = r2;

        const float bb0 = a3 + E0, bb1 = b3 + E1, bb2 = c3 + E2;
        const float cc0 = q23_0 + E0, cc1 = q23_1 + E1, cc2 = q23_2 + E2;

        const float A  = (tm == 0) ? q012_0 : (tm == 2) ? q012_1 : q012_2;
        const float Bv = (tm == 0) ? bb0   : (tm == 2) ? bb1   : bb2;
        const float C  = (tm == 1) ? cc0   : (tm == 0) ? cc1   : cc2;
        const float D  = (tm == 2) ? q123_0 : (tm == 1) ? q123_1 : q123_2;

        f32x4 o;
        o.x = __shfl(A,  srcA) + bv.x;
        o.y = __shfl(Bv, srcA) + bv.y;
        o.z = __shfl(C,  srcC) + bv.z;
        o.w = __shfl(D,  srcD) + bv.w;

        __builtin_nontemporal_store(
            o, reinterpret_cast<f32x4*>(out + O0 + 4 * t));   // 16B-aligned
    }
}

extern "C" void kernel_launch(void* const* d_in, const int* in_sizes, int n_in,
                              void* d_out, int out_size, void* d_ws, size_t ws_size,
                              hipStream_t stream) {
    const float* x    = (const float*)d_in[0];
    const float* w    = (const float*)d_in[1];
    const float* bias = (const float*)d_in[2];
    float* out        = (float*)d_out;
    float* ws         = (float*)d_ws;

    build_ext_kernel<<<(WEXT_N + BEXT_N + 255) / 256, 256, 0, stream>>>(w, bias, ws);
    diag_flat_kernel<<<1024, 256, 0, stream>>>(x, ws, out);
}

// Round 13
// 118.933 us; speedup vs baseline: 1.3573x; 1.0136x over previous
//
#include <hip/hip_runtime.h>

// FINAL — best-measured variant (R7: 119.0 us = 5.08 TB/s effective).
// out[b,g] = sum_f x[b,3g+f]*w[3g+f] + bias[g];  B=4096, G=9229, F=3, fp32.
//
// Flat decomposition: output i = b*G+g <-> x floats 3i..3i+2 (seamless
// across rows). Unit = 256 outputs = 192 aligned x-f4s read + 64 aligned
// out-f4s written, both nontemporal (zero-reuse streams; NT-store beat
// cached-store by 2.5% in R10's A/B). Weight wrap at gene G handled by
// wrap-extended copies wext/bext in d_ws (setup kernel).
// Grid 2048x256 = 32 waves/CU (grid 1024 was neutral, R11).
//
// In-register shuffle reassembly (verified R5-R11):
//   f4 j (slot s=j/64, lane t=j%64), m=(s+t)%3:
//   m=0: gene4k=p0+p1+p2; gene4k+1=p3+next(p0+p1)
//   m=1: gene4k+2=p2+p3+next(p0); m=2: gene4k+3=p1+p2+p3
//   ring shfl(t+1), lane63 slot-wrap; output transpose via 4 pull-shfls
//   (lane t collects genes 4t..4t+3 from lanes (3t+i)&63, CRT-unique).
//
// Roofline: 453.6 MB read + 151.2 MB write = 604.8 MB unavoidable
// (FETCH/WRITE counters confirm). 119 us = 81% of the 1:1 copy ceiling
// (6.29 TB/s) on a 75R/25W mix. Nine structural theories A/B'd; all
// residuals <3%.

#define G       9229
#define GFW     27687            // 3*G
#define NUNIT   147664           // 37,801,984 / 256
#define NWAVES  8192             // grid 2048 x 4 waves
#define WEXT_N  (GFW + 768)      // 28455
#define BEXT_OFF 28456           // float offset of bext in ws (16B aligned)
#define BEXT_N  (G + 256)        // 9485
#define WS_FLOATS (BEXT_OFF + BEXT_N)   // 37941 -> 151764 bytes

typedef float f32x4 __attribute__((ext_vector_type(4)));

__global__ __launch_bounds__(256) void build_ext_kernel(
    const float* __restrict__ w, const float* __restrict__ bias,
    float* __restrict__ ws) {
    const int i = (int)blockIdx.x * 256 + (int)threadIdx.x;
    if (i < WEXT_N) {
        ws[i] = w[i >= GFW ? i - GFW : i];
    } else {
        const int k = i - WEXT_N;
        if (k < BEXT_N) ws[BEXT_OFF + k] = bias[k >= G ? k - G : k];
    }
}

__global__ __launch_bounds__(256, 8) void diag_flat_kernel(
    const float* __restrict__ x,
    const float* __restrict__ ws,
    float* __restrict__ out) {

    const float* wext = ws;
    const float* bext = ws + BEXT_OFF;

    const int t  = (int)(threadIdx.x & 63);
    const int wv = (int)blockIdx.x * 4 + (int)(threadIdx.x >> 6);

    const int tm    = t % 3;
    const bool last = (t == 63);
    const int srcA = (3 * t) & 63;
    const int srcC = (3 * t + 1) & 63;
    const int srcD = (3 * t + 2) & 63;

    for (unsigned u = (unsigned)wv; u < NUNIT; u += NWAVES) {
        const unsigned O0  = 256u * u;          // first output of unit
        const unsigned g0  = O0 % (unsigned)G;  // gene of first output
        const unsigned wf0 = 3u * g0;           // weight float base (wrap-free in wext)
        const float* xr = x + 768u * u;         // 16B-aligned

        const f32x4 v0 = __builtin_nontemporal_load(
            reinterpret_cast<const f32x4*>(xr + 4 * t));
        const f32x4 v1 = __builtin_nontemporal_load(
            reinterpret_cast<const f32x4*>(xr + 256 + 4 * t));
        const f32x4 v2 = __builtin_nontemporal_load(
            reinterpret_cast<const f32x4*>(xr + 512 + 4 * t));

        // cached, dword-aligned (16B-misaligned ok), L1/L2-resident
        const float4 w0 = *reinterpret_cast<const float4*>(wext + wf0 + 4 * t);
        const float4 w1 = *reinterpret_cast<const float4*>(wext + wf0 + 256 + 4 * t);
        const float4 w2 = *reinterpret_cast<const float4*>(wext + wf0 + 512 + 4 * t);
        const float4 bv = *reinterpret_cast<const float4*>(bext + g0 + 4 * t);

        // slot products / partials
        const float a0 = v0.x * w0.x, a1 = v0.y * w0.y, a2 = v0.z * w0.z, a3 = v0.w * w0.w;
        const float q01_0 = a0 + a1, q23_0 = a2 + a3;
        const float q012_0 = q01_0 + a2, q123_0 = q23_0 + a1;
        const float b0 = v1.x * w1.x, b1 = v1.y * w1.y, b2 = v1.z * w1.z, b3 = v1.w * w1.w;
        const float q01_1 = b0 + b1, q23_1 = b2 + b3;
        const float q012_1 = q01_1 + b2, q123_1 = q23_1 + b1;
        const float c0 = v2.x * w2.x, c1 = v2.y * w2.y, c2 = v2.z * w2.z, c3 = v2.w * w2.w;
        const float q01_2 = c0 + c1, q23_2 = c2 + c3;
        const float q012_2 = q01_2 + c2, q123_2 = q23_2 + c1;

        // ring exchange: pred (f4 j-1) needs: m==1 -> p0+p1 ; m==2 -> p0
        const float s0 = (tm == 1) ? q01_0 : a0;
        const float s1 = (tm == 0) ? q01_1 : b0;
        const float s2 = (tm == 2) ? q01_2 : c0;
        const float r0 = __shfl(s0, (t + 1) & 63);
        const float r1 = __shfl(s1, (t + 1) & 63);
        const float r2 = __shfl(s2, (t + 1) & 63);
        const float E0 = last ? r1 : r0;
        const float E1 = last ? r2 : r1;
        const float E2 = r2;

        const float bb0 = a3 + E0, bb1 = b3 + E1, bb2 = c3 + E2;
        const float cc0 = q23_0 + E0, cc1 = q23_1 + E1, cc2 = q23_2 + E2;

        const float A  = (tm == 0) ? q012_0 : (tm == 2) ? q012_1 : q012_2;
        const float Bv = (tm == 0) ? bb0   : (tm == 2) ? bb1   : bb2;
        const float C  = (tm == 1) ? cc0   : (tm == 0) ? cc1   : cc2;
        const float D  = (tm == 2) ? q123_0 : (tm == 1) ? q123_1 : q123_2;

        f32x4 o;
        o.x = __shfl(A,  srcA) + bv.x;
        o.y = __shfl(Bv, srcA) + bv.y;
        o.z = __shfl(C,  srcC) + bv.z;
        o.w = __shfl(D,  srcD) + bv.w;

        __builtin_nontemporal_store(
            o, reinterpret_cast<f32x4*>(out + O0 + 4 * t));   // 16B-aligned
    }
}

extern "C" void kernel_launch(void* const* d_in, const int* in_sizes, int n_in,
                              void* d_out, int out_size, void* d_ws, size_t ws_size,
                              hipStream_t stream) {
    const float* x    = (const float*)d_in[0];
    const float* w    = (const float*)d_in[1];
    const float* bias = (const float*)d_in[2];
    float* out        = (float*)d_out;
    float* ws         = (float*)d_ws;

    build_ext_kernel<<<(WEXT_N + BEXT_N + 255) / 256, 256, 0, stream>>>(w, bias, ws);
    diag_flat_kernel<<<2048, 256, 0, stream>>>(x, ws, out);
}